// Round 5
// baseline (626.165 us; speedup 1.0000x reference)
//
#include <hip/hip_runtime.h>

#define NN 30000
#define NE 120000
#define NG 256
#define FIN 16
#define HD 32
#define TOUT 10
#define EPSV 1e-5f

__device__ __forceinline__ void atomAddF(float* p, float v) {
    unsafeAtomicAdd(p, v);  // global_atomic_add_f32
}

// ===========================================================================
// Mono preprocessing: CSR by destination + per-graph node counts.
// ONE block of 1024 threads. In-degree counts live in LDS as packed u16
// pairs (max indeg ~25 << 65536), scanned in-LDS, scatter via global cursor
// atomics. Replaces 5 kernels + 1 memset.
// ===========================================================================
__global__ __launch_bounds__(1024) void build_csr(
    const int* __restrict__ eidx, const int* __restrict__ batch,
    int*  __restrict__ row_start,  // [NN+1]
    int*  __restrict__ cursor,     // [NN]
    int2* __restrict__ csr,        // [NE] (edge id, src id)
    float* __restrict__ deg_g)     // [NG], pre-zeroed
{
    __shared__ int packed[NN / 2];   // two u16 counts per int (60 KB)
    __shared__ int wsum[16];
    __shared__ int carry_s;

    const int t = threadIdx.x, lane = t & 63, w = t >> 6;

    for (int ii = t; ii < NN / 2; ii += 1024) packed[ii] = 0;
    if (t == 0) carry_s = 0;
    __syncthreads();

    // count in-degrees (LDS atomics; packed halves can't overflow)
    for (int e = t; e < NE; e += 1024) {
        const int d = eidx[NE + e];
        atomicAdd(&packed[d >> 1], 1 << ((d & 1) << 4));
    }
    __syncthreads();

    // exclusive scan over pair-sums (15000 entries, 15 chunks of 1024)
    for (int base = 0; base < NN / 2; base += 1024) {
        const int idx = base + t;
        const int pv = (idx < NN / 2) ? packed[idx] : 0;
        const int lo = pv & 0xffff;
        const int v  = lo + (pv >> 16);
        int s = v;
        #pragma unroll
        for (int off = 1; off < 64; off <<= 1) {
            const int u = __shfl_up(s, off, 64);
            if (lane >= off) s += u;
        }
        if (lane == 63) wsum[w] = s;
        __syncthreads();
        if (w == 0) {
            int ws = (lane < 16) ? wsum[lane] : 0;
            #pragma unroll
            for (int off = 1; off < 16; off <<= 1) {
                const int u = __shfl_up(ws, off, 64);
                if (lane >= off) ws += u;
            }
            if (lane < 16) wsum[lane] = ws;
        }
        __syncthreads();
        const int incl  = s + ((w > 0) ? wsum[w - 1] : 0);
        const int carry = carry_s;
        if (idx < NN / 2) {
            const int excl = carry + incl - v;
            *(int2*)(row_start + 2 * idx) = make_int2(excl, excl + lo);
            *(int2*)(cursor    + 2 * idx) = make_int2(excl, excl + lo);
        }
        __syncthreads();                  // all reads of carry_s done
        if (t == 1023) carry_s += incl;   // chunk total
        __syncthreads();
    }
    if (t == 0) row_start[NN] = NE;
    __syncthreads();  // barrier drains vmcnt -> cursor stores visible at L2

    // scatter edges into CSR slots
    for (int e = t; e < NE; e += 1024) {
        const int d = eidx[NE + e];
        const int slot = atomicAdd(&cursor[d], 1);
        csr[slot] = make_int2(e, eidx[e]);
    }

    // per-graph node counts (batch sorted -> run-length, 1 atomic per run)
    for (int base = 0; base < NN; base += 1024) {
        const int n = base + t;
        const int g = (n < NN) ? batch[n] : -1;
        const int prev = __shfl_up(g, 1);
        const bool head = (lane == 0) || (g != prev);
        const unsigned long long heads = __ballot(head);
        if (head && g >= 0) {
            const unsigned long long higher =
                (lane < 63) ? (heads >> (lane + 1)) : 0ULL;
            const int next = higher ? (lane + __ffsll(higher)) : 64;
            atomAddF(&deg_g[g], (float)(next - lane));
        }
    }
}

// ===========================================================================
// Fused layer. Block = 16 nodes, 4 waves.
// Phase A: each wave gathers 4 nodes (2 pr-halves x 2 j-iters), writes
//          T[n][k] (k = f*IN+i, 10 rows: 8 nn_w coeffs, sum_x, own row).
// Phase B: k split 4 ways across waves; lane (h,o) holds K/8 W values in
//          REGISTERS (loaded once from global/L2). T read as half-wave-
//          broadcast ds_read_b128. Partials -> LDS P -> reduce + epilogue.
// ===========================================================================
template<int IN, bool FINAL>
__global__ __launch_bounds__(256) void fused_layer(
    const float* __restrict__ hin,       // [NN, IN]
    const float* __restrict__ ea,        // [NE, 8]
    const int2*  __restrict__ csr,       // [NE] (e, s) grouped by dst
    const int*   __restrict__ row_start, // [NN+1]
    const float* __restrict__ nn_w,      // [8, IN*32]  flat k*32+o, k=f*IN+i
    const float* __restrict__ nn_b,      // [IN*32]
    const float* __restrict__ root,      // [IN*32]
    const float* __restrict__ bias,      // [32]
    const int*   __restrict__ batch,
    const float* __restrict__ deg_g,     // [NG]
    const float* __restrict__ bn_g,
    const float* __restrict__ bn_b,
    const float* __restrict__ bn_m,
    const float* __restrict__ bn_v,
    float*       __restrict__ out)       // [NN,32] or pooled [NG,32]
{
    constexpr int K  = 10 * IN;   // flattened contraction dim
    constexpr int KQ = K / 4;     // per-wave k-slice
    constexpr int KL = KQ / 2;    // per-lane-half W registers
    constexpr int NQ = 32 / IN;   // edge subgroups per node in phase A

    __shared__ float Tlds[16 * K];
    __shared__ float P[4 * 16 * 64];

    const int tid = threadIdx.x;
    const int wv  = tid >> 6;
    const int l   = tid & 63;
    const int h   = l >> 5;
    const int o   = l & 31;
    const int l5  = l & 31;
    const int pr  = l >> 5;

    // ---- W slice into registers (global loads, L2-resident, once/block) ---
    float Wreg[KL];
    const int kbase = wv * KQ + h * KL;
    #pragma unroll
    for (int kk = 0; kk < KL; ++kk) {
        const int k = kbase + kk;
        const float* src = (k < 8 * IN) ? (nn_w + k * 32)
                         : (k < 9 * IN) ? (nn_b + (k - 8 * IN) * 32)
                                        : (root + (k - 9 * IN) * 32);
        Wreg[kk] = src[o];
    }

    // ---------------- phase A: gather + per-edge rank-1 -------------------
    const int i = l5 & (IN - 1);
    const int q = l5 / IN;   // 0 for IN=32; 0/1 for IN=16

    #pragma unroll
    for (int j = 0; j < 2; ++j) {
        const int nloc = wv * 4 + j * 2 + pr;
        const int d    = blockIdx.x * 16 + nloc;   // NN%16==0: in range

        float t[9];
        #pragma unroll
        for (int f = 0; f < 9; ++f) t[f] = 0.0f;

        const int p0 = row_start[d];
        const int p1 = row_start[d + 1];

        int p = p0 + q;
        int2 es = (p < p1) ? csr[p] : make_int2(0, 0);
        float  xv = hin[(long)es.y * IN + i];
        float4 a  = *(const float4*)(ea + (long)es.x * 8);
        float4 b  = *(const float4*)(ea + (long)es.x * 8 + 4);

        while (p < p1) {
            const int pn = p + NQ;
            const int2 esn = (pn < p1) ? csr[pn] : make_int2(0, 0);
            const float  xvn = hin[(long)esn.y * IN + i];
            const float4 an  = *(const float4*)(ea + (long)esn.x * 8);
            const float4 bn  = *(const float4*)(ea + (long)esn.x * 8 + 4);

            t[0] = fmaf(a.x, xv, t[0]);
            t[1] = fmaf(a.y, xv, t[1]);
            t[2] = fmaf(a.z, xv, t[2]);
            t[3] = fmaf(a.w, xv, t[3]);
            t[4] = fmaf(b.x, xv, t[4]);
            t[5] = fmaf(b.y, xv, t[5]);
            t[6] = fmaf(b.z, xv, t[6]);
            t[7] = fmaf(b.w, xv, t[7]);
            t[8] += xv;

            p = pn; es = esn; xv = xvn; a = an; b = bn;
        }

        if (IN == 16) {   // combine the 2 edge subgroups (same i)
            #pragma unroll
            for (int f = 0; f < 9; ++f) t[f] += __shfl_xor(t[f], 16, 64);
        }

        if (l5 < IN) {
            float* tb = Tlds + nloc * K;
            #pragma unroll
            for (int f = 0; f < 9; ++f) tb[f * IN + i] = t[f];
            tb[9 * IN + i] = hin[(long)d * IN + i];   // own row (root term)
        }
    }
    __syncthreads();

    // ---------------- phase B: partial GEMM over this wave's k-slice ------
    for (int n = 0; n < 16; ++n) {
        const float* tb = Tlds + n * K + kbase;
        float acc = 0.0f;
        #pragma unroll
        for (int kq = 0; kq < KL / 4; ++kq) {
            const float4 tv = *(const float4*)(tb + kq * 4);
            acc = fmaf(Wreg[4 * kq + 0], tv.x, acc);
            acc = fmaf(Wreg[4 * kq + 1], tv.y, acc);
            acc = fmaf(Wreg[4 * kq + 2], tv.z, acc);
            acc = fmaf(Wreg[4 * kq + 3], tv.w, acc);
        }
        P[(wv * 16 + n) * 64 + l] = acc;
    }
    __syncthreads();

    // ---------------- reduce partials + epilogue ---------------------------
    #pragma unroll
    for (int r = 0; r < 2; ++r) {
        const int idx = r * 256 + tid;          // 512 (n,o) pairs
        const int n   = idx >> 5;
        const int oo  = idx & 31;
        float sum = bias[oo];
        #pragma unroll
        for (int ww = 0; ww < 4; ++ww) {
            const float* pb = P + (ww * 16 + n) * 64;
            sum += pb[oo] + pb[32 + oo];
        }
        const int d = blockIdx.x * 16 + n;
        const int g = batch[d];
        if (!FINAL) {
            float dg = deg_g[g];
            dg = dg > 0.0f ? dg : 1.0f;
            float v = sum * (1.0f / sqrtf(dg));
            const float s = bn_g[oo] / sqrtf(bn_v[oo] + EPSV);
            v = (v - bn_m[oo]) * s + bn_b[oo];
            out[(long)d * 32 + oo] = v > 0.0f ? v : 0.0f;
        } else {
            // merge adjacent-node pair within wave before pool atomic
            float v = sum;
            const int   g2 = __shfl(g, (tid & 63) ^ 32, 64);
            const float v2 = __shfl(v, (tid & 63) ^ 32, 64);
            bool do_store = true;
            if (g2 == g) {
                if (tid & 32) do_store = false;
                else          v += v2;
            }
            if (do_store) atomAddF(&out[g * 32 + oo], v);
        }
    }
}

// ---------------------------------------------------------------------------
// Head: pooled/cnt -> relu(@w1+b1) @ w2 + b2. One thread per graph.
// ---------------------------------------------------------------------------
__global__ __launch_bounds__(64) void head_kernel(
    const float* __restrict__ pooled,
    const float* __restrict__ deg,
    const float* __restrict__ w1,
    const float* __restrict__ b1,
    const float* __restrict__ w2,
    const float* __restrict__ b2,
    float*       __restrict__ out)
{
    const int g = blockIdx.x * 64 + threadIdx.x;
    if (g >= NG) return;
    float cnt = deg[g];
    cnt = cnt > 1.0f ? cnt : 1.0f;

    float p[HD];
    #pragma unroll
    for (int i = 0; i < HD; ++i) p[i] = pooled[g * HD + i] / cnt;

    float hid[HD];
    #pragma unroll
    for (int j = 0; j < HD; ++j) {
        float a = b1[j];
        #pragma unroll
        for (int i = 0; i < HD; ++i)
            a = fmaf(p[i], w1[i * HD + j], a);
        hid[j] = a > 0.0f ? a : 0.0f;
    }
    #pragma unroll
    for (int t = 0; t < TOUT; ++t) {
        float a = b2[t];
        #pragma unroll
        for (int j = 0; j < HD; ++j)
            a = fmaf(hid[j], w2[j * TOUT + t], a);
        out[g * TOUT + t] = a;
    }
}

// ---------------------------------------------------------------------------
extern "C" void kernel_launch(void* const* d_in, const int* in_sizes, int n_in,
                              void* d_out, int out_size, void* d_ws, size_t ws_size,
                              hipStream_t stream)
{
    const float* x        = (const float*)d_in[0];
    const float* ea       = (const float*)d_in[1];
    const int*   eidx     = (const int*)  d_in[2];
    const int*   batch    = (const int*)  d_in[3];
    const float* c1_nn_w  = (const float*)d_in[4];
    const float* c1_nn_b  = (const float*)d_in[5];
    const float* c1_root  = (const float*)d_in[6];
    const float* c1_bias  = (const float*)d_in[7];
    const float* c2_nn_w  = (const float*)d_in[8];
    const float* c2_nn_b  = (const float*)d_in[9];
    const float* c2_root  = (const float*)d_in[10];
    const float* c2_bias  = (const float*)d_in[11];
    const float* c3_nn_w  = (const float*)d_in[12];
    const float* c3_nn_b  = (const float*)d_in[13];
    const float* c3_root  = (const float*)d_in[14];
    const float* c3_bias  = (const float*)d_in[15];
    const float* bn1_g    = (const float*)d_in[16];
    const float* bn1_b    = (const float*)d_in[17];
    const float* bn1_m    = (const float*)d_in[18];
    const float* bn1_v    = (const float*)d_in[19];
    const float* bn2_g    = (const float*)d_in[20];
    const float* bn2_b    = (const float*)d_in[21];
    const float* bn2_m    = (const float*)d_in[22];
    const float* bn2_v    = (const float*)d_in[23];
    const float* mlp_w1   = (const float*)d_in[24];
    const float* mlp_b1   = (const float*)d_in[25];
    const float* mlp_w2   = (const float*)d_in[26];
    const float* mlp_b2   = (const float*)d_in[27];
    float* out = (float*)d_out;

    // workspace layout (deg_g and pooled adjacent -> single memset)
    float* h1     = (float*)d_ws;            // NN*32
    float* h2     = h1 + NN * HD;            // NN*32
    float* deg_g  = h2 + NN * HD;            // NG
    float* pooled = deg_g + NG;              // NG*32
    int*   ibase  = (int*)(pooled + NG * HD);
    int2*  csr    = (int2*)ibase;            // NE int2
    int*   row_s  = ibase + 2 * NE;          // NN+1
    int*   cursor = row_s + NN + 2;          // NN (keep csr int2 8B-aligned)

    hipMemsetAsync(deg_g, 0, sizeof(float) * (NG + NG * HD), stream);

    build_csr<<<1, 1024, 0, stream>>>(eidx, batch, row_s, cursor, csr, deg_g);

    const int lgrid = NN / 16;  // 1875 blocks, 16 nodes each

    fused_layer<FIN, false><<<lgrid, 256, 0, stream>>>(
        x, ea, csr, row_s, c1_nn_w, c1_nn_b, c1_root, c1_bias,
        batch, deg_g, bn1_g, bn1_b, bn1_m, bn1_v, h1);

    fused_layer<HD, false><<<lgrid, 256, 0, stream>>>(
        h1, ea, csr, row_s, c2_nn_w, c2_nn_b, c2_root, c2_bias,
        batch, deg_g, bn2_g, bn2_b, bn2_m, bn2_v, h2);

    fused_layer<HD, true><<<lgrid, 256, 0, stream>>>(
        h2, ea, csr, row_s, c3_nn_w, c3_nn_b, c3_root, c3_bias,
        batch, deg_g, nullptr, nullptr, nullptr, nullptr, pooled);

    head_kernel<<<(NG + 63) / 64, 64, 0, stream>>>(pooled, deg_g, mlp_w1, mlp_b1,
                                                   mlp_w2, mlp_b2, out);
}

// Round 6
// 240.578 us; speedup vs baseline: 2.6028x; 2.6028x over previous
//
#include <hip/hip_runtime.h>

#define NN 30000
#define NE 120000
#define NG 256
#define FIN 16
#define HD 32
#define TOUT 10
#define EPSV 1e-5f
#define NB_SCAN 30   // ceil(NN/1024)

__device__ __forceinline__ void atomAddF(float* p, float v) {
    unsafeAtomicAdd(p, v);  // global_atomic_add_f32
}

// ---------------------------------------------------------------------------
// Per-edge in-degree count + per-graph node count (run-length on sorted batch)
// ---------------------------------------------------------------------------
__global__ __launch_bounds__(256) void count_deg_kernel(
    const int* __restrict__ eidx, const int* __restrict__ batch,
    int* __restrict__ deg_in, float* __restrict__ deg_g)
{
    const int t = blockIdx.x * 256 + threadIdx.x;
    if (t < NE) atomicAdd(&deg_in[eidx[NE + t]], 1);

    const int lane = threadIdx.x & 63;
    const int g = (t < NN) ? batch[t] : -1;
    const int prev = __shfl_up(g, 1);
    const bool head = (lane == 0) || (g != prev);
    const unsigned long long heads = __ballot(head);
    if (head && g >= 0) {
        const unsigned long long higher =
            (lane < 63) ? (heads >> (lane + 1)) : 0ULL;
        const int next = higher ? (lane + __ffsll(higher)) : 64;
        atomAddF(&deg_g[g], (float)(next - lane));
    }
}

// ---------------------------------------------------------------------------
// Scan phase 1: per-block exclusive scan of deg_in; emit block sums.
// ---------------------------------------------------------------------------
__global__ __launch_bounds__(1024) void scan_phase1(
    const int* __restrict__ deg_in, int* __restrict__ row_start,
    int* __restrict__ blocksum)
{
    __shared__ int wsum[16];
    const int t = threadIdx.x, lane = t & 63, w = t >> 6;
    const int idx = blockIdx.x * 1024 + t;
    const int v = (idx < NN) ? deg_in[idx] : 0;
    int s = v;
    #pragma unroll
    for (int off = 1; off < 64; off <<= 1) {
        const int u = __shfl_up(s, off, 64);
        if (lane >= off) s += u;
    }
    if (lane == 63) wsum[w] = s;
    __syncthreads();
    if (w == 0) {
        int ws = (lane < 16) ? wsum[lane] : 0;
        #pragma unroll
        for (int off = 1; off < 16; off <<= 1) {
            const int u = __shfl_up(ws, off, 64);
            if (lane >= off) ws += u;
        }
        if (lane < 16) wsum[lane] = ws;
    }
    __syncthreads();
    const int incl = s + ((w > 0) ? wsum[w - 1] : 0);
    if (idx < NN) row_start[idx] = incl - v;  // block-local exclusive
    if (t == 1023) blocksum[blockIdx.x] = incl;
}

// ---------------------------------------------------------------------------
// Scan apply: each block reduces blocksum[0..blk) itself (30 values) and
// adds the offset; writes row_start and cursor. Folds old phase2 into phase3.
// ---------------------------------------------------------------------------
__global__ __launch_bounds__(1024) void scan_apply(
    const int* __restrict__ blocksum, int* __restrict__ row_start,
    int* __restrict__ cursor)
{
    __shared__ int boff_s;
    const int t = threadIdx.x;
    if (t < 64) {
        int v = (t < blockIdx.x) ? blocksum[t] : 0;   // blockIdx.x <= 29
        #pragma unroll
        for (int off = 32; off > 0; off >>= 1) v += __shfl_down(v, off, 64);
        if (t == 0) boff_s = v;
    }
    __syncthreads();
    const int idx = blockIdx.x * 1024 + t;
    if (idx < NN) {
        const int r = row_start[idx] + boff_s;
        row_start[idx] = r;
        cursor[idx]    = r;
    }
    if (blockIdx.x == 0 && t == 0) row_start[NN] = NE;
}

// ---------------------------------------------------------------------------
// Scatter edges into CSR order AND reorder ea/src into CSR order so the
// layer's inner loop reads contiguous memory (kills the e-indirection hop).
// ---------------------------------------------------------------------------
__global__ __launch_bounds__(256) void csr_scatter(
    const int* __restrict__ eidx, const float* __restrict__ ea,
    int* __restrict__ cursor,
    int* __restrict__ src_s,      // [NE+8]
    float4* __restrict__ ea_s)    // [(NE+8)*2]
{
    const int e = blockIdx.x * 256 + threadIdx.x;
    if (e < NE) {
        const int d = eidx[NE + e];
        const int slot = atomicAdd(&cursor[d], 1);
        src_s[slot] = eidx[e];
        const float4* s4 = (const float4*)(ea + (size_t)e * 8);
        ea_s[2 * slot]     = s4[0];
        ea_s[2 * slot + 1] = s4[1];
    }
    if (e < 8) src_s[NE + e] = 0;   // pipeline overshoot pad (safe hin[0])
}

// ===========================================================================
// Fused layer. Block = 16 nodes, 4 waves.
// Phase A: wave handles 4 nodes (2 halves x 2 j); per node, IN lanes (i),
//          depth-2 pipelined loop over CSR-ordered src/ea (contiguous).
// Phase B: k = f*IN+i flattened (K=10*IN); k split 4 ways across waves;
//          lane (h,o) holds K/8 W values in registers (global/L2, once).
//          T read as half-wave-broadcast ds_read_b128 -> partials in P ->
//          block reduce + epilogue (gsn+BN+ReLU, or pool atomics).
// ===========================================================================
template<int IN, bool FINAL>
__global__ __launch_bounds__(256) void fused_layer(
    const float* __restrict__ hin,       // [NN, IN]
    const int*   __restrict__ src_s,     // [NE+8] CSR-ordered src ids
    const float4* __restrict__ ea_s,     // [(NE+8)*2] CSR-ordered edge attrs
    const int*   __restrict__ row_start, // [NN+1]
    const float* __restrict__ nn_w,      // [8*IN*32] flat k*32+o
    const float* __restrict__ nn_b,      // [IN*32]
    const float* __restrict__ root,      // [IN*32]
    const float* __restrict__ bias,      // [32]
    const int*   __restrict__ batch,
    const float* __restrict__ deg_g,     // [NG]
    const float* __restrict__ bn_g,
    const float* __restrict__ bn_b,
    const float* __restrict__ bn_m,
    const float* __restrict__ bn_v,
    float*       __restrict__ out)       // [NN,32] or pooled [NG,32]
{
    constexpr int K  = 10 * IN;
    constexpr int KQ = K / 4;
    constexpr int KL = KQ / 2;
    constexpr int NQ = 32 / IN;   // edge subgroups per node (1 or 2)

    __shared__ float Tlds[16 * K];
    __shared__ float P[4 * 16 * 64];

    const int tid = threadIdx.x;
    const int wv  = tid >> 6;
    const int l   = tid & 63;
    const int h   = l >> 5;
    const int o   = l & 31;
    const int l5  = l & 31;
    const int pr  = l >> 5;

    // ---- W slice into registers (L2-hot global loads, once per block) ----
    float Wreg[KL];
    const int kbase = wv * KQ + h * KL;
    #pragma unroll
    for (int kk = 0; kk < KL; ++kk) {
        const int k = kbase + kk;
        const float* src = (k < 8 * IN) ? (nn_w + k * 32)
                         : (k < 9 * IN) ? (nn_b + (k - 8 * IN) * 32)
                                        : (root + (k - 9 * IN) * 32);
        Wreg[kk] = src[o];
    }

    // ---------------- phase A ------------------------------------------
    const int i = l5 & (IN - 1);
    const int q = l5 / IN;

    #pragma unroll
    for (int j = 0; j < 2; ++j) {
        const int nloc = wv * 4 + j * 2 + pr;
        const int d    = blockIdx.x * 16 + nloc;   // NN%16==0

        float t[9];
        #pragma unroll
        for (int f = 0; f < 9; ++f) t[f] = 0.0f;

        const int p0 = row_start[d];
        const int p1 = row_start[d + 1];

        int p = p0 + q;
        if (p < p1) {
            // depth-2 pipeline: src 2 ahead, x/ea 1 ahead
            int pn     = p + NQ;
            int s_cur  = src_s[p];
            int s_nxt  = src_s[pn];                 // pad-safe
            float4 a_c = ea_s[2 * p];
            float4 b_c = ea_s[2 * p + 1];
            float  xv  = hin[(long)s_cur * IN + i];

            while (true) {
                const float4 a_n = ea_s[2 * pn];        // pad-safe
                const float4 b_n = ea_s[2 * pn + 1];
                const float  xvn = hin[(long)s_nxt * IN + i];
                const int pn2    = pn + NQ;
                const int s_n2   = src_s[pn2];          // pad-safe

                t[0] = fmaf(a_c.x, xv, t[0]);
                t[1] = fmaf(a_c.y, xv, t[1]);
                t[2] = fmaf(a_c.z, xv, t[2]);
                t[3] = fmaf(a_c.w, xv, t[3]);
                t[4] = fmaf(b_c.x, xv, t[4]);
                t[5] = fmaf(b_c.y, xv, t[5]);
                t[6] = fmaf(b_c.z, xv, t[6]);
                t[7] = fmaf(b_c.w, xv, t[7]);
                t[8] += xv;

                p = pn;
                if (p >= p1) break;
                pn = pn2; s_nxt = s_n2;
                a_c = a_n; b_c = b_n; xv = xvn;
            }
        }

        if (IN == 16) {   // combine the 2 edge subgroups (same i)
            #pragma unroll
            for (int f = 0; f < 9; ++f) t[f] += __shfl_xor(t[f], 16, 64);
        }

        if (l5 < IN) {
            float* tb = Tlds + nloc * K;
            #pragma unroll
            for (int f = 0; f < 9; ++f) tb[f * IN + i] = t[f];
            tb[9 * IN + i] = hin[(long)d * IN + i];   // own row (root term)
        }
    }
    __syncthreads();

    // ---------------- phase B: partial GEMM over this wave's k-slice ------
    for (int n = 0; n < 16; ++n) {
        const float* tb = Tlds + n * K + kbase;
        float acc = 0.0f;
        #pragma unroll
        for (int kq = 0; kq < KL / 4; ++kq) {
            const float4 tv = *(const float4*)(tb + kq * 4);
            acc = fmaf(Wreg[4 * kq + 0], tv.x, acc);
            acc = fmaf(Wreg[4 * kq + 1], tv.y, acc);
            acc = fmaf(Wreg[4 * kq + 2], tv.z, acc);
            acc = fmaf(Wreg[4 * kq + 3], tv.w, acc);
        }
        P[(wv * 16 + n) * 64 + l] = acc;
    }
    __syncthreads();

    // ---------------- reduce partials + epilogue ---------------------------
    #pragma unroll
    for (int r = 0; r < 2; ++r) {
        const int idx = r * 256 + tid;          // 512 (n,o) pairs
        const int n   = idx >> 5;
        const int oo  = idx & 31;
        float sum = bias[oo];
        #pragma unroll
        for (int ww = 0; ww < 4; ++ww) {
            const float* pb = P + (ww * 16 + n) * 64;
            sum += pb[oo] + pb[32 + oo];
        }
        const int d = blockIdx.x * 16 + n;
        const int g = batch[d];
        if (!FINAL) {
            float dg = deg_g[g];
            dg = dg > 0.0f ? dg : 1.0f;
            float v = sum * (1.0f / sqrtf(dg));
            const float s = bn_g[oo] / sqrtf(bn_v[oo] + EPSV);
            v = (v - bn_m[oo]) * s + bn_b[oo];
            out[(long)d * 32 + oo] = v > 0.0f ? v : 0.0f;
        } else {
            float v = sum;
            const int   g2 = __shfl(g, (tid & 63) ^ 32, 64);
            const float v2 = __shfl(v, (tid & 63) ^ 32, 64);
            bool do_store = true;
            if (g2 == g) {                  // merge adjacent-node pair
                if (tid & 32) do_store = false;
                else          v += v2;
            }
            if (do_store) atomAddF(&out[g * 32 + oo], v);
        }
    }
}

// ---------------------------------------------------------------------------
// Head: pooled/cnt -> relu(@w1+b1) @ w2 + b2. One thread per graph.
// ---------------------------------------------------------------------------
__global__ __launch_bounds__(64) void head_kernel(
    const float* __restrict__ pooled,
    const float* __restrict__ deg,
    const float* __restrict__ w1,
    const float* __restrict__ b1,
    const float* __restrict__ w2,
    const float* __restrict__ b2,
    float*       __restrict__ out)
{
    const int g = blockIdx.x * 64 + threadIdx.x;
    if (g >= NG) return;
    float cnt = deg[g];
    cnt = cnt > 1.0f ? cnt : 1.0f;

    float p[HD];
    #pragma unroll
    for (int i = 0; i < HD; ++i) p[i] = pooled[g * HD + i] / cnt;

    float hid[HD];
    #pragma unroll
    for (int j = 0; j < HD; ++j) {
        float a = b1[j];
        #pragma unroll
        for (int i = 0; i < HD; ++i)
            a = fmaf(p[i], w1[i * HD + j], a);
        hid[j] = a > 0.0f ? a : 0.0f;
    }
    #pragma unroll
    for (int t = 0; t < TOUT; ++t) {
        float a = b2[t];
        #pragma unroll
        for (int j = 0; j < HD; ++j)
            a = fmaf(hid[j], w2[j * TOUT + t], a);
        out[g * TOUT + t] = a;
    }
}

// ---------------------------------------------------------------------------
extern "C" void kernel_launch(void* const* d_in, const int* in_sizes, int n_in,
                              void* d_out, int out_size, void* d_ws, size_t ws_size,
                              hipStream_t stream)
{
    const float* x        = (const float*)d_in[0];
    const float* ea       = (const float*)d_in[1];
    const int*   eidx     = (const int*)  d_in[2];
    const int*   batch    = (const int*)  d_in[3];
    const float* c1_nn_w  = (const float*)d_in[4];
    const float* c1_nn_b  = (const float*)d_in[5];
    const float* c1_root  = (const float*)d_in[6];
    const float* c1_bias  = (const float*)d_in[7];
    const float* c2_nn_w  = (const float*)d_in[8];
    const float* c2_nn_b  = (const float*)d_in[9];
    const float* c2_root  = (const float*)d_in[10];
    const float* c2_bias  = (const float*)d_in[11];
    const float* c3_nn_w  = (const float*)d_in[12];
    const float* c3_nn_b  = (const float*)d_in[13];
    const float* c3_root  = (const float*)d_in[14];
    const float* c3_bias  = (const float*)d_in[15];
    const float* bn1_g    = (const float*)d_in[16];
    const float* bn1_b    = (const float*)d_in[17];
    const float* bn1_m    = (const float*)d_in[18];
    const float* bn1_v    = (const float*)d_in[19];
    const float* bn2_g    = (const float*)d_in[20];
    const float* bn2_b    = (const float*)d_in[21];
    const float* bn2_m    = (const float*)d_in[22];
    const float* bn2_v    = (const float*)d_in[23];
    const float* mlp_w1   = (const float*)d_in[24];
    const float* mlp_b1   = (const float*)d_in[25];
    const float* mlp_w2   = (const float*)d_in[26];
    const float* mlp_b2   = (const float*)d_in[27];
    float* out = (float*)d_out;

    // workspace layout (all segment sizes keep 16B alignment)
    float*  h1     = (float*)d_ws;             // NN*32
    float*  h2     = h1 + NN * HD;             // NN*32
    float*  deg_g  = h2 + NN * HD;             // NG
    float*  pooled = deg_g + NG;               // NG*32
    float4* ea_s   = (float4*)(pooled + NG * HD);  // (NE+8)*2 float4
    int*    src_s  = (int*)(ea_s + 2 * (NE + 8));  // NE+8
    int*    deg_in = src_s + NE + 8;           // NN
    int*    row_s  = deg_in + NN;              // NN+1
    int*    cursor = row_s + NN + 1;           // NN
    int*    bsum   = cursor + NN;              // NB_SCAN

    hipMemsetAsync(deg_in, 0, sizeof(int) * NN, stream);
    hipMemsetAsync(deg_g,  0, sizeof(float) * (NG + NG * HD), stream);

    const int egrid = (NE + 255) / 256;

    count_deg_kernel<<<egrid, 256, 0, stream>>>(eidx, batch, deg_in, deg_g);
    scan_phase1<<<NB_SCAN, 1024, 0, stream>>>(deg_in, row_s, bsum);
    scan_apply <<<NB_SCAN, 1024, 0, stream>>>(bsum, row_s, cursor);
    csr_scatter<<<egrid, 256, 0, stream>>>(eidx, ea, cursor, src_s, ea_s);

    const int lgrid = NN / 16;  // 1875 blocks, 16 nodes each

    fused_layer<FIN, false><<<lgrid, 256, 0, stream>>>(
        x, src_s, ea_s, row_s, c1_nn_w, c1_nn_b, c1_root, c1_bias,
        batch, deg_g, bn1_g, bn1_b, bn1_m, bn1_v, h1);

    fused_layer<HD, false><<<lgrid, 256, 0, stream>>>(
        h1, src_s, ea_s, row_s, c2_nn_w, c2_nn_b, c2_root, c2_bias,
        batch, deg_g, bn2_g, bn2_b, bn2_m, bn2_v, h2);

    fused_layer<HD, true><<<lgrid, 256, 0, stream>>>(
        h2, src_s, ea_s, row_s, c3_nn_w, c3_nn_b, c3_root, c3_bias,
        batch, deg_g, nullptr, nullptr, nullptr, nullptr, pooled);

    head_kernel<<<(NG + 63) / 64, 64, 0, stream>>>(pooled, deg_g, mlp_w1, mlp_b1,
                                                   mlp_w2, mlp_b2, out);
}